// Round 1
// baseline (568.725 us; speedup 1.0000x reference)
//
#include <hip/hip_runtime.h>
#include <hip/hip_bf16.h>

typedef __bf16 bf16x8 __attribute__((ext_vector_type(8)));
typedef __bf16 bf16x4 __attribute__((ext_vector_type(4)));
typedef float floatx4 __attribute__((ext_vector_type(4)));

// ---------------------------------------------------------------------------
// Elementwise f32 -> bf16 convert (x). n must be divisible by 4.
// ---------------------------------------------------------------------------
__global__ __launch_bounds__(256) void cvt_f32_bf16(const float* __restrict__ src,
                                                    __bf16* __restrict__ dst, int n) {
    int i = (blockIdx.x * 256 + threadIdx.x) * 4;
    if (i + 3 < n) {
        const float4 v = *(const float4*)(src + i);
        bf16x4 o;
        o[0] = (__bf16)v.x; o[1] = (__bf16)v.y; o[2] = (__bf16)v.z; o[3] = (__bf16)v.w;
        *(bf16x4*)(dst + i) = o;
    }
}

// ---------------------------------------------------------------------------
// Transpose + convert: src [R][C] f32 row-major -> dst[c][r] bf16, for c < C.
// R must be divisible by 64. 64x64 LDS tile, coalesced read & write.
// ---------------------------------------------------------------------------
__global__ __launch_bounds__(256) void transpose_cvt(const float* __restrict__ src,
                                                     __bf16* __restrict__ dst,
                                                     int R, int C) {
    __shared__ __bf16 tile[64][65];
    const int r0 = blockIdx.x * 64;
    const int c0 = blockIdx.y * 64;
    const int t  = threadIdx.x;
#pragma unroll
    for (int rep = 0; rep < 16; ++rep) {
        int lin = rep * 256 + t;
        int sr = lin >> 6, sc = lin & 63;
        int c = c0 + sc;
        float v = (c < C) ? src[(size_t)(r0 + sr) * C + c] : 0.f;
        tile[sc][sr] = (__bf16)v;
    }
    __syncthreads();
#pragma unroll
    for (int rep = 0; rep < 16; ++rep) {
        int lin = rep * 256 + t;
        int dr = lin >> 6, dc = lin & 63;
        int c = c0 + dr;
        if (c < C) dst[(size_t)c * R + r0 + dc] = tile[dr][dc];
    }
}

// ---------------------------------------------------------------------------
// GEMM: C[M,Nstore] = act(A[M,K] @ Bt[Ntile,K]^T + bias), m97 structure.
//   A row-major [M,K] bf16, Bt row-major [>=gridN*128, K] bf16.
//   128x128 block tile, BK=64, 4 waves (2x2), each wave 64x64 via 4x4 MFMA
//   16x16x32 frags. global_load_lds width=16 staging, ds_read_b128 frags.
//   M % 128 == 0, K % 64 == 0 required. Column store guarded by col < Nstore.
// ---------------------------------------------------------------------------
template <bool RELU, bool OUT_BF16>
__global__ __launch_bounds__(256, 2) void gemm_bt(const __bf16* __restrict__ A,
                                                  const __bf16* __restrict__ Bt,
                                                  const float* __restrict__ bias,
                                                  void* __restrict__ Cv,
                                                  int M, int K, int Nstore) {
    __shared__ __bf16 sA[128 * 64];
    __shared__ __bf16 sB[128 * 64];

    const int tid   = threadIdx.x;
    const int lane  = tid & 63;
    const int wave  = tid >> 6;
    const int wr    = wave >> 1;   // wave row (0..1)
    const int wc    = wave & 1;    // wave col (0..1)
    const int mBase = blockIdx.y * 128;
    const int nBase = blockIdx.x * 128;

    const int lr = lane >> 4;      // quad 0..3
    const int lc = lane & 15;

    floatx4 acc[4][4];
#pragma unroll
    for (int i = 0; i < 4; ++i)
#pragma unroll
        for (int j = 0; j < 4; ++j) acc[i][j] = (floatx4)0.f;

    for (int k0 = 0; k0 < K; k0 += 64) {
        // ---- stage A,B tiles: 128 rows x 64 bf16 (128 B) each ----
#pragma unroll
        for (int it = 0; it < 4; ++it) {
            int lin = it * 256 + tid;          // 0..1023 -> one 16B chunk each
            int r   = lin >> 3;                // tile row 0..127
            int kc  = lin & 7;                 // 16B chunk within row
            const __bf16* ga = A  + (size_t)(mBase + r) * K + k0 + kc * 8;
            const __bf16* gb = Bt + (size_t)(nBase + r) * K + k0 + kc * 8;
            __builtin_amdgcn_global_load_lds(
                (__attribute__((address_space(1))) void*)ga,
                (__attribute__((address_space(3))) void*)(sA + lin * 8), 16, 0, 0);
            __builtin_amdgcn_global_load_lds(
                (__attribute__((address_space(1))) void*)gb,
                (__attribute__((address_space(3))) void*)(sB + lin * 8), 16, 0, 0);
        }
        __builtin_amdgcn_s_waitcnt(0);
        __syncthreads();

        // ---- compute: 2 k-chunks of 32, 4x4 MFMA tiles per wave ----
#pragma unroll
        for (int kk = 0; kk < 2; ++kk) {
            bf16x8 af[4], bfr[4];
#pragma unroll
            for (int i = 0; i < 4; ++i)
                af[i] = *(const bf16x8*)(sA + (wr * 64 + i * 16 + lc) * 64 + kk * 32 + lr * 8);
#pragma unroll
            for (int j = 0; j < 4; ++j)
                bfr[j] = *(const bf16x8*)(sB + (wc * 64 + j * 16 + lc) * 64 + kk * 32 + lr * 8);
#pragma unroll
            for (int i = 0; i < 4; ++i)
#pragma unroll
                for (int j = 0; j < 4; ++j)
                    acc[i][j] = __builtin_amdgcn_mfma_f32_16x16x32_bf16(af[i], bfr[j], acc[i][j], 0, 0, 0);
        }
        __syncthreads();
    }

    // ---- epilogue: bias + activation + store (C/D: col=lane&15, row=quad*4+reg) ----
#pragma unroll
    for (int j = 0; j < 4; ++j) {
        int col = nBase + wc * 64 + j * 16 + lc;
        bool ok = (col < Nstore);
        float bv = ok ? bias[col] : 0.f;
        if (ok) {
#pragma unroll
            for (int i = 0; i < 4; ++i) {
                int rowb = mBase + wr * 64 + i * 16 + lr * 4;
#pragma unroll
                for (int r = 0; r < 4; ++r) {
                    float v = acc[i][j][r] + bv;
                    if (RELU) v = fmaxf(v, 0.f);
                    if (OUT_BF16)
                        ((__bf16*)Cv)[(size_t)(rowb + r) * Nstore + col] = (__bf16)v;
                    else
                        ((float*)Cv)[(size_t)(rowb + r) * Nstore + col] = v;
                }
            }
        }
    }
}

// ---------------------------------------------------------------------------
// Problem constants
// ---------------------------------------------------------------------------
#define B_    4096
#define IN_   2048
#define HID_  4096
#define NC_   1000
#define NCP_  1024   // padded classes for tiling

extern "C" void kernel_launch(void* const* d_in, const int* in_sizes, int n_in,
                              void* d_out, int out_size, void* d_ws, size_t ws_size,
                              hipStream_t stream) {
    const float* x  = (const float*)d_in[0];
    const float* w1 = (const float*)d_in[1];
    const float* b1 = (const float*)d_in[2];
    const float* w2 = (const float*)d_in[3];
    const float* b2 = (const float*)d_in[4];
    const float* w3 = (const float*)d_in[5];
    const float* b3 = (const float*)d_in[6];
    float* out = (float*)d_out;

    // Workspace layout (bytes). h2 aliases xb+w1t (dead after gemm1). 109 MB total.
    char* ws = (char*)d_ws;
    __bf16* xb  = (__bf16*)(ws);                       // [4096][2048] 16.8 MB
    __bf16* w1t = (__bf16*)(ws + (16u << 20));         // [4096][2048] 16.8 MB
    __bf16* w2t = (__bf16*)(ws + (32u << 20));         // [4096][4096] 33.6 MB
    __bf16* w3t = (__bf16*)(ws + (64u << 20));         // [1024][4096]  8.4 MB
    __bf16* h1  = (__bf16*)(ws + (72u << 20));         // [4096][4096] 33.6 MB
    __bf16* h2  = (__bf16*)(ws);                       // [4096][4096] alias over xb/w1t

    // 1) convert x to bf16
    cvt_f32_bf16<<<(B_ * IN_) / 1024, 256, 0, stream>>>(x, xb, B_ * IN_);
    // 2) transpose+convert weights to [N][K] bf16
    transpose_cvt<<<dim3(IN_ / 64, HID_ / 64), 256, 0, stream>>>(w1, w1t, IN_, HID_);
    transpose_cvt<<<dim3(HID_ / 64, HID_ / 64), 256, 0, stream>>>(w2, w2t, HID_, HID_);
    transpose_cvt<<<dim3(HID_ / 64, NCP_ / 64), 256, 0, stream>>>(w3, w3t, HID_, NC_);
    // 3) three fused GEMMs
    gemm_bt<true, true><<<dim3(HID_ / 128, B_ / 128), 256, 0, stream>>>(
        xb, w1t, b1, h1, B_, IN_, HID_);
    gemm_bt<true, true><<<dim3(HID_ / 128, B_ / 128), 256, 0, stream>>>(
        h1, w2t, b2, h2, B_, HID_, HID_);
    gemm_bt<false, false><<<dim3(NCP_ / 128, B_ / 128), 256, 0, stream>>>(
        h2, w3t, b3, out, B_, HID_, NC_);
}

// Round 2
// 427.713 us; speedup vs baseline: 1.3297x; 1.3297x over previous
//
#include <hip/hip_runtime.h>
#include <hip/hip_bf16.h>

typedef __bf16 bf16x8 __attribute__((ext_vector_type(8)));
typedef __bf16 bf16x4 __attribute__((ext_vector_type(4)));
typedef float floatx4 __attribute__((ext_vector_type(4)));

#define B_    4096
#define IN_   2048
#define HID_  4096
#define NC_   1000
#define NCP_  1024

// ---------------------------------------------------------------------------
// Elementwise f32 -> bf16 convert. n divisible by 8.
// ---------------------------------------------------------------------------
__global__ __launch_bounds__(256) void cvt_f32_bf16(const float* __restrict__ src,
                                                    __bf16* __restrict__ dst, int n) {
    int i = (blockIdx.x * 256 + threadIdx.x) * 8;
    if (i + 7 < n) {
        float4 a = *(const float4*)(src + i);
        float4 b = *(const float4*)(src + i + 4);
        bf16x8 o;
        o[0] = (__bf16)a.x; o[1] = (__bf16)a.y; o[2] = (__bf16)a.z; o[3] = (__bf16)a.w;
        o[4] = (__bf16)b.x; o[5] = (__bf16)b.y; o[6] = (__bf16)b.z; o[7] = (__bf16)b.w;
        *(bf16x8*)(dst + i) = o;
    }
}

// ---------------------------------------------------------------------------
// Transpose + convert: src [R][C] f32 -> dst [c][r] bf16 for all c in
// [0, gridDim.y*64) (rows >= C are zero-filled; dst must be padded).
// f32 LDS tile stride 65 dwords: phase-1 writes conflict-free (bank = r+c),
// phase-2 reads ~2-way. float4 global loads, bf16x4 global stores.
// ---------------------------------------------------------------------------
__global__ __launch_bounds__(256) void transpose_cvt(const float* __restrict__ src,
                                                     __bf16* __restrict__ dst,
                                                     int R, int C) {
    __shared__ float tile[64 * 65];
    const int r0 = blockIdx.x * 64;
    const int c0 = blockIdx.y * 64;
    const int t  = threadIdx.x;
#pragma unroll
    for (int it = 0; it < 4; ++it) {
        int lin = it * 256 + t;
        int sr = lin >> 4, c4 = lin & 15;
        int cb = c0 + c4 * 4;
        const float* s = src + (size_t)(r0 + sr) * C;
        float4 v;
        if (cb + 3 < C) {
            v = *(const float4*)(s + cb);
        } else {
            v.x = (cb + 0 < C) ? s[cb + 0] : 0.f;
            v.y = (cb + 1 < C) ? s[cb + 1] : 0.f;
            v.z = (cb + 2 < C) ? s[cb + 2] : 0.f;
            v.w = (cb + 3 < C) ? s[cb + 3] : 0.f;
        }
        tile[(c4 * 4 + 0) * 65 + sr] = v.x;
        tile[(c4 * 4 + 1) * 65 + sr] = v.y;
        tile[(c4 * 4 + 2) * 65 + sr] = v.z;
        tile[(c4 * 4 + 3) * 65 + sr] = v.w;
    }
    __syncthreads();
#pragma unroll
    for (int it = 0; it < 4; ++it) {
        int lin = it * 256 + t;
        int dr = lin >> 4, q4 = lin & 15;
        bf16x4 o;
#pragma unroll
        for (int j = 0; j < 4; ++j) o[j] = (__bf16)tile[dr * 65 + q4 * 4 + j];
        *(bf16x4*)(dst + (size_t)(c0 + dr) * R + r0 + q4 * 4) = o;
    }
}

// ---------------------------------------------------------------------------
// GEMM: C = act(A[M,K] @ Bt[N,K]^T + bias). m97 structure + XOR swizzle:
// LDS slot (r, c) holds global 16B-chunk (r, c ^ (r&7)); fragment reads use
// chunk q^(lc&7) so each ds_read_b128 spreads over all 8 bank groups.
// ---------------------------------------------------------------------------
template <bool RELU, bool OUT_BF16>
__global__ __launch_bounds__(256, 2) void gemm_bt(const __bf16* __restrict__ A,
                                                  const __bf16* __restrict__ Bt,
                                                  const float* __restrict__ bias,
                                                  void* __restrict__ Cv,
                                                  int M, int K, int Nstore) {
    __shared__ __bf16 sA[128 * 64];
    __shared__ __bf16 sB[128 * 64];

    const int tid   = threadIdx.x;
    const int lane  = tid & 63;
    const int wave  = tid >> 6;
    const int wr    = wave >> 1;
    const int wc    = wave & 1;
    const int mBase = blockIdx.y * 128;
    const int nBase = blockIdx.x * 128;
    const int lr    = lane >> 4;
    const int lc    = lane & 15;

    floatx4 acc[4][4];
#pragma unroll
    for (int i = 0; i < 4; ++i)
#pragma unroll
        for (int j = 0; j < 4; ++j) acc[i][j] = (floatx4)0.f;

    for (int k0 = 0; k0 < K; k0 += 64) {
#pragma unroll
        for (int it = 0; it < 4; ++it) {
            int lin = it * 256 + tid;
            int r   = lin >> 3;
            int kc  = (lin & 7) ^ (r & 7);          // XOR swizzle
            const __bf16* ga = A  + (size_t)(mBase + r) * K + k0 + kc * 8;
            const __bf16* gb = Bt + (size_t)(nBase + r) * K + k0 + kc * 8;
            __builtin_amdgcn_global_load_lds(
                (__attribute__((address_space(1))) void*)ga,
                (__attribute__((address_space(3))) void*)(sA + lin * 8), 16, 0, 0);
            __builtin_amdgcn_global_load_lds(
                (__attribute__((address_space(1))) void*)gb,
                (__attribute__((address_space(3))) void*)(sB + lin * 8), 16, 0, 0);
        }
        __builtin_amdgcn_s_waitcnt(0);
        __syncthreads();

#pragma unroll
        for (int kk = 0; kk < 2; ++kk) {
            const int sw = (kk * 4 + lr) ^ (lc & 7);   // swizzled chunk
            bf16x8 af[4], bfr[4];
#pragma unroll
            for (int i = 0; i < 4; ++i)
                af[i] = *(const bf16x8*)(sA + (wr * 64 + i * 16 + lc) * 64 + sw * 8);
#pragma unroll
            for (int j = 0; j < 4; ++j)
                bfr[j] = *(const bf16x8*)(sB + (wc * 64 + j * 16 + lc) * 64 + sw * 8);
#pragma unroll
            for (int i = 0; i < 4; ++i)
#pragma unroll
                for (int j = 0; j < 4; ++j)
                    acc[i][j] = __builtin_amdgcn_mfma_f32_16x16x32_bf16(af[i], bfr[j], acc[i][j], 0, 0, 0);
        }
        __syncthreads();
    }

#pragma unroll
    for (int j = 0; j < 4; ++j) {
        int col = nBase + wc * 64 + j * 16 + lc;
        if (col < Nstore) {
            float bv = bias[col];
#pragma unroll
            for (int i = 0; i < 4; ++i) {
                int rowb = mBase + wr * 64 + i * 16 + lr * 4;
#pragma unroll
                for (int r = 0; r < 4; ++r) {
                    float v = acc[i][j][r] + bv;
                    if (RELU) v = fmaxf(v, 0.f);
                    if (OUT_BF16)
                        ((__bf16*)Cv)[(size_t)(rowb + r) * Nstore + col] = (__bf16)v;
                    else
                        ((float*)Cv)[(size_t)(rowb + r) * Nstore + col] = v;
                }
            }
        }
    }
}

// ---------------------------------------------------------------------------
// Split-K GEMM partial: P[z][M][1024] = A[:, z*KH:(z+1)*KH] @ Bt^T (f32,
// no bias/act). Same body as gemm_bt, z = blockIdx.z. N fixed 1024.
// ---------------------------------------------------------------------------
__global__ __launch_bounds__(256, 2) void gemm_sk(const __bf16* __restrict__ A,
                                                  const __bf16* __restrict__ Bt,
                                                  float* __restrict__ P,
                                                  int M, int KH, int Ktot) {
    __shared__ __bf16 sA[128 * 64];
    __shared__ __bf16 sB[128 * 64];

    const int tid   = threadIdx.x;
    const int lane  = tid & 63;
    const int wave  = tid >> 6;
    const int wr    = wave >> 1;
    const int wc    = wave & 1;
    const int mBase = blockIdx.y * 128;
    const int nBase = blockIdx.x * 128;
    const int z     = blockIdx.z;
    const int kOff  = z * KH;
    const int lr    = lane >> 4;
    const int lc    = lane & 15;

    floatx4 acc[4][4];
#pragma unroll
    for (int i = 0; i < 4; ++i)
#pragma unroll
        for (int j = 0; j < 4; ++j) acc[i][j] = (floatx4)0.f;

    for (int k0 = kOff; k0 < kOff + KH; k0 += 64) {
#pragma unroll
        for (int it = 0; it < 4; ++it) {
            int lin = it * 256 + tid;
            int r   = lin >> 3;
            int kc  = (lin & 7) ^ (r & 7);
            const __bf16* ga = A  + (size_t)(mBase + r) * Ktot + k0 + kc * 8;
            const __bf16* gb = Bt + (size_t)(nBase + r) * Ktot + k0 + kc * 8;
            __builtin_amdgcn_global_load_lds(
                (__attribute__((address_space(1))) void*)ga,
                (__attribute__((address_space(3))) void*)(sA + lin * 8), 16, 0, 0);
            __builtin_amdgcn_global_load_lds(
                (__attribute__((address_space(1))) void*)gb,
                (__attribute__((address_space(3))) void*)(sB + lin * 8), 16, 0, 0);
        }
        __builtin_amdgcn_s_waitcnt(0);
        __syncthreads();

#pragma unroll
        for (int kk = 0; kk < 2; ++kk) {
            const int sw = (kk * 4 + lr) ^ (lc & 7);
            bf16x8 af[4], bfr[4];
#pragma unroll
            for (int i = 0; i < 4; ++i)
                af[i] = *(const bf16x8*)(sA + (wr * 64 + i * 16 + lc) * 64 + sw * 8);
#pragma unroll
            for (int j = 0; j < 4; ++j)
                bfr[j] = *(const bf16x8*)(sB + (wc * 64 + j * 16 + lc) * 64 + sw * 8);
#pragma unroll
            for (int i = 0; i < 4; ++i)
#pragma unroll
                for (int j = 0; j < 4; ++j)
                    acc[i][j] = __builtin_amdgcn_mfma_f32_16x16x32_bf16(af[i], bfr[j], acc[i][j], 0, 0, 0);
        }
        __syncthreads();
    }

    float* Pz = P + (size_t)z * M * NCP_;
#pragma unroll
    for (int j = 0; j < 4; ++j) {
        int col = nBase + wc * 64 + j * 16 + lc;
#pragma unroll
        for (int i = 0; i < 4; ++i) {
            int rowb = mBase + wr * 64 + i * 16 + lr * 4;
#pragma unroll
            for (int r = 0; r < 4; ++r)
                Pz[(size_t)(rowb + r) * NCP_ + col] = acc[i][j][r];
        }
    }
}

// ---------------------------------------------------------------------------
// out[m][c] = P0[m][c] + P1[m][c] + b3[c], c < 1000. grid (4, 4096).
// ---------------------------------------------------------------------------
__global__ __launch_bounds__(256) void reduce_bias(const float* __restrict__ P,
                                                   const float* __restrict__ b3,
                                                   float* __restrict__ out) {
    int c = blockIdx.x * 256 + threadIdx.x;
    int m = blockIdx.y;
    if (c < NC_)
        out[(size_t)m * NC_ + c] =
            P[(size_t)m * NCP_ + c] + P[(size_t)(B_ + m) * NCP_ + c] + b3[c];
}

extern "C" void kernel_launch(void* const* d_in, const int* in_sizes, int n_in,
                              void* d_out, int out_size, void* d_ws, size_t ws_size,
                              hipStream_t stream) {
    const float* x  = (const float*)d_in[0];
    const float* w1 = (const float*)d_in[1];
    const float* b1 = (const float*)d_in[2];
    const float* w2 = (const float*)d_in[3];
    const float* b2 = (const float*)d_in[4];
    const float* w3 = (const float*)d_in[5];
    const float* b3 = (const float*)d_in[6];
    float* out = (float*)d_out;

    // ws layout (MiB): [0,16) xb | [16,32) w1t | [32,64) w2t | [64,72) w3t |
    // [72,104) h1 -> later split-K partials P (32 MiB) | h2 aliases [0,32).
    char* ws = (char*)d_ws;
    __bf16* xb  = (__bf16*)(ws);
    __bf16* w1t = (__bf16*)(ws + (16u << 20));
    __bf16* w2t = (__bf16*)(ws + (32u << 20));
    __bf16* w3t = (__bf16*)(ws + (64u << 20));
    __bf16* h1  = (__bf16*)(ws + (72u << 20));
    __bf16* h2  = (__bf16*)(ws);                 // over xb/w1t (dead after gemm1)
    float*  P   = (float*)(ws + (72u << 20));    // over h1 (dead after gemm2)

    cvt_f32_bf16<<<(B_ * IN_) / 2048, 256, 0, stream>>>(x, xb, B_ * IN_);
    transpose_cvt<<<dim3(IN_ / 64, HID_ / 64), 256, 0, stream>>>(w1, w1t, IN_, HID_);
    transpose_cvt<<<dim3(HID_ / 64, HID_ / 64), 256, 0, stream>>>(w2, w2t, HID_, HID_);
    transpose_cvt<<<dim3(HID_ / 64, NCP_ / 64), 256, 0, stream>>>(w3, w3t, HID_, NC_);

    gemm_bt<true, true><<<dim3(HID_ / 128, B_ / 128), 256, 0, stream>>>(
        xb, w1t, b1, h1, B_, IN_, HID_);
    gemm_bt<true, true><<<dim3(HID_ / 128, B_ / 128), 256, 0, stream>>>(
        h1, w2t, b2, h2, B_, HID_, HID_);

    gemm_sk<<<dim3(NCP_ / 128, B_ / 128, 2), 256, 0, stream>>>(
        h2, w3t, P, B_, HID_ / 2, HID_);
    reduce_bias<<<dim3(NCP_ / 256, B_), 256, 0, stream>>>(P, b3, out);
}